// Round 1
// baseline (2691.285 us; speedup 1.0000x reference)
//
#include <hip/hip_runtime.h>

// H2GCNConv: out[:, 0:128]  = segment_sum(vals1[e] * x[col1[e]], row1)
//            out[:, 128:256] = segment_sum(vals2[e] * x[col2[e]], row2)
// N=50000, D=128, fp32. Baseline: one wave per edge, atomic scatter.

constexpr int D = 128;
constexpr int OUT_STRIDE = 256; // concat of two D=128 halves

__launch_bounds__(256)
__global__ void spmm_scatter(const int* __restrict__ row,
                             const int* __restrict__ col,
                             const float* __restrict__ vals,
                             const float* __restrict__ x,
                             float* __restrict__ out,
                             int n_edges, int col_off) {
    const int wave = (int)((blockIdx.x * (unsigned)blockDim.x + threadIdx.x) >> 6);
    const int lane = threadIdx.x & 63;
    if (wave >= n_edges) return;

    const int   r = row[wave];   // wave-uniform address -> single broadcast request
    const int   c = col[wave];
    const float v = vals[wave];

    // 64 lanes x float2 = 128 floats, fully coalesced 512B row read
    const float2 xv = ((const float2*)x)[(size_t)c * (D / 2) + lane];

    float* o = out + (size_t)r * OUT_STRIDE + col_off + 2 * lane;
    // native global_atomic_add_f32 (plain atomicAdd may lower to a CAS loop)
    unsafeAtomicAdd(o,     v * xv.x);
    unsafeAtomicAdd(o + 1, v * xv.y);
}

extern "C" void kernel_launch(void* const* d_in, const int* in_sizes, int n_in,
                              void* d_out, int out_size, void* d_ws, size_t ws_size,
                              hipStream_t stream) {
    const float* x     = (const float*)d_in[0];
    const int*   row1  = (const int*)  d_in[1];
    const int*   col1  = (const int*)  d_in[2];
    const float* vals1 = (const float*)d_in[3];
    const int*   row2  = (const int*)  d_in[4];
    const int*   col2  = (const int*)  d_in[5];
    const float* vals2 = (const float*)d_in[6];
    float* out = (float*)d_out;

    const int e1 = in_sizes[1];
    const int e2 = in_sizes[4];

    // d_out is re-poisoned (0xAA) before every timed replay -> must zero it here.
    hipMemsetAsync(out, 0, (size_t)out_size * sizeof(float), stream);

    // one wave per edge, 4 waves per 256-thread block
    const int wpb = 4;
    spmm_scatter<<<(e1 + wpb - 1) / wpb, 256, 0, stream>>>(row1, col1, vals1, x, out, e1, 0);
    spmm_scatter<<<(e2 + wpb - 1) / wpb, 256, 0, stream>>>(row2, col2, vals2, x, out, e2, D);
}

// Round 3
// 712.353 us; speedup vs baseline: 3.7780x; 3.7780x over previous
//
#include <hip/hip_runtime.h>

// H2GCNConv: out[:, 0:128]  = segment_sum(vals1[e] * x[col1[e]], row1)
//            out[:, 128:256] = segment_sum(vals2[e] * x[col2[e]], row2)
// N=50000, D=128, fp32.
// Round 3: CSR build with IMMUTABLE starts array (scan output never mutated);
// bin uses separate cursor arrays. Gather reads only pristine scan output.

constexpr int D = 128;
constexpr int OUT_STRIDE = 256;

// ---------- step 1: histogram (counts into starts[0..n-1]) ----------
__launch_bounds__(256)
__global__ void hist_kernel(const int* __restrict__ row, int n,
                            int* __restrict__ counts) {
    const int i = blockIdx.x * blockDim.x + threadIdx.x;
    if (i < n) atomicAdd(&counts[row[i]], 1);
}

// ---------- step 2: single-block exclusive scan over n elements, in place ----------
__launch_bounds__(1024)
__global__ void exscan_kernel(int* __restrict__ a, int n) {
    __shared__ int wsum[16];
    __shared__ int carry;
    __shared__ int tot;
    const int tid  = threadIdx.x;
    const int lane = tid & 63;
    const int wid  = tid >> 6;
    if (tid == 0) carry = 0;
    __syncthreads();
    for (int base = 0; base < n; base += 1024) {
        const int i = base + tid;
        int v = (i < n) ? a[i] : 0;
        int acc = v;
        #pragma unroll
        for (int d = 1; d < 64; d <<= 1) {
            int t = __shfl_up(acc, d);
            if (lane >= d) acc += t;
        }
        if (lane == 63) wsum[wid] = acc;
        __syncthreads();
        if (wid == 0) {
            int wv = (lane < 16) ? wsum[lane] : 0;
            int wacc = wv;
            #pragma unroll
            for (int d = 1; d < 16; d <<= 1) {
                int t = __shfl_up(wacc, d);
                if (lane >= d) wacc += t;
            }
            if (lane == 15) tot = wacc;             // chunk total
            if (lane < 16)  wsum[lane] = wacc - wv; // exclusive wave offsets
        }
        __syncthreads();
        const int excl = acc - v + wsum[wid] + carry;
        if (i < n) a[i] = excl;
        __syncthreads();
        if (tid == 0) carry += tot;
        __syncthreads();
    }
}

// ---------- step 3: bin edges into CSR order (starts is read-only) ----------
__launch_bounds__(256)
__global__ void bin_kernel(const int* __restrict__ row,
                           const int* __restrict__ col,
                           const float* __restrict__ vals, int n,
                           const int* __restrict__ starts,  // pristine scan output
                           int* __restrict__ cur,           // zeroed cursors
                           int2* __restrict__ edges) {
    const int i = blockIdx.x * blockDim.x + threadIdx.x;
    if (i < n) {
        const int r = row[i];
        const int p = starts[r] + atomicAdd(&cur[r], 1);
        edges[p] = make_int2(col[i], __float_as_int(vals[i]));
    }
}

// ---------- step 4: gather, one wave per row ----------
__launch_bounds__(256)
__global__ void spmm_gather(const int* __restrict__ starts,  // n+1 entries, immutable
                            const int2* __restrict__ edges,
                            const float* __restrict__ x,
                            float* __restrict__ out,
                            int n_rows, int n_edges, int col_off) {
    const int wave = (int)((blockIdx.x * (unsigned)blockDim.x + threadIdx.x) >> 6);
    const int lane = threadIdx.x & 63;
    if (wave >= n_rows) return;
    int start = starts[wave];
    int end   = starts[wave + 1];
    // wave-uniform robustness clamps (no wild reads even on corrupt metadata)
    if (start < 0) start = 0;
    if (end > n_edges) end = n_edges;

    float2 acc = make_float2(0.f, 0.f);
    int j = start;
    for (; j + 1 < end; j += 2) {              // 2 x-row loads in flight
        const int2 e0 = edges[j];
        const int2 e1 = edges[j + 1];
        const float v0 = __int_as_float(e0.y);
        const float v1 = __int_as_float(e1.y);
        const float2 a0 = ((const float2*)x)[(size_t)e0.x * (D / 2) + lane];
        const float2 a1 = ((const float2*)x)[(size_t)e1.x * (D / 2) + lane];
        acc.x += v0 * a0.x; acc.y += v0 * a0.y;
        acc.x += v1 * a1.x; acc.y += v1 * a1.y;
    }
    if (j < end) {
        const int2 e = edges[j];
        const float v = __int_as_float(e.y);
        const float2 a = ((const float2*)x)[(size_t)e.x * (D / 2) + lane];
        acc.x += v * a.x; acc.y += v * a.y;
    }
    ((float2*)(out + (size_t)wave * OUT_STRIDE + col_off))[lane] = acc;
}

extern "C" void kernel_launch(void* const* d_in, const int* in_sizes, int n_in,
                              void* d_out, int out_size, void* d_ws, size_t ws_size,
                              hipStream_t stream) {
    const float* x     = (const float*)d_in[0];
    const int*   row1  = (const int*)  d_in[1];
    const int*   col1  = (const int*)  d_in[2];
    const float* vals1 = (const float*)d_in[3];
    const int*   row2  = (const int*)  d_in[4];
    const int*   col2  = (const int*)  d_in[5];
    const float* vals2 = (const float*)d_in[6];
    float* out = (float*)d_out;

    const int e1 = in_sizes[1];
    const int e2 = in_sizes[4];
    const int n_rows = out_size / OUT_STRIDE;    // 50000

    // workspace layout, 16B-aligned regions
    const size_t S = (((size_t)(n_rows + 1) * sizeof(int)) + 15) & ~(size_t)15;
    const size_t starts1_off = 0;
    const size_t starts2_off = S;
    const size_t cur1_off    = 2 * S;
    const size_t cur2_off    = 2 * S + (size_t)n_rows * sizeof(int);
    const size_t zero_bytes  = 2 * S + 2 * (size_t)n_rows * sizeof(int);
    const size_t edges1_off  = (zero_bytes + 15) & ~(size_t)15;
    const size_t edges2_off  = edges1_off + (size_t)e1 * sizeof(int2);
    const size_t ws_needed   = edges2_off + (size_t)e2 * sizeof(int2);
    (void)ws_needed; // ws_size is ample (checked: ~26.4 MB needed)

    int*  starts1 = (int*)((char*)d_ws + starts1_off);
    int*  starts2 = (int*)((char*)d_ws + starts2_off);
    int*  cur1    = (int*)((char*)d_ws + cur1_off);
    int*  cur2    = (int*)((char*)d_ws + cur2_off);
    int2* edges1  = (int2*)((char*)d_ws + edges1_off);
    int2* edges2  = (int2*)((char*)d_ws + edges2_off);

    // zero starts1, starts2, cur1, cur2 in one shot (contiguous prefix)
    hipMemsetAsync(d_ws, 0, zero_bytes, stream);

    hist_kernel<<<(e1 + 255) / 256, 256, 0, stream>>>(row1, e1, starts1);
    hist_kernel<<<(e2 + 255) / 256, 256, 0, stream>>>(row2, e2, starts2);

    // scan n+1 entries: starts[n] ends up = total edge count
    exscan_kernel<<<1, 1024, 0, stream>>>(starts1, n_rows + 1);
    exscan_kernel<<<1, 1024, 0, stream>>>(starts2, n_rows + 1);

    bin_kernel<<<(e1 + 255) / 256, 256, 0, stream>>>(row1, col1, vals1, e1, starts1, cur1, edges1);
    bin_kernel<<<(e2 + 255) / 256, 256, 0, stream>>>(row2, col2, vals2, e2, starts2, cur2, edges2);

    // gather: one wave per row; writes cover every output element (no out memset)
    const int gblocks = (n_rows * 64 + 255) / 256;
    spmm_gather<<<gblocks, 256, 0, stream>>>(starts1, edges1, x, out, n_rows, e1, 0);
    spmm_gather<<<gblocks, 256, 0, stream>>>(starts2, edges2, x, out, n_rows, e2, D);
}

// Round 4
// 598.933 us; speedup vs baseline: 4.4935x; 1.1894x over previous
//
#include <hip/hip_runtime.h>

// H2GCNConv: out[:, 0:128]  = segment_sum(vals1[e] * x[col1[e]], row1)
//            out[:, 128:256] = segment_sum(vals2[e] * x[col2[e]], row2)
// N=50000, D=128, fp32 in/out.
// Round 4: CSR build (immutable starts) + bf16-staged x for the gather,
// parallel 2-pass scan, fused hist/bin/gather launches.

constexpr int D = 128;
constexpr int OUT_STRIDE = 256;

// fp32 -> bf16 round-to-nearest-even
__device__ __forceinline__ unsigned short f2b(float f) {
    unsigned u = __float_as_uint(f);
    u += 0x7fffu + ((u >> 16) & 1u);
    return (unsigned short)(u >> 16);
}

// ---------- x fp32 -> bf16 staging ----------
__launch_bounds__(256)
__global__ void cvt_kernel(const float4* __restrict__ x, ushort4* __restrict__ xb, int n4) {
    const int i = blockIdx.x * 256 + threadIdx.x;
    if (i < n4) {
        const float4 v = x[i];
        ushort4 o;
        o.x = f2b(v.x); o.y = f2b(v.y); o.z = f2b(v.z); o.w = f2b(v.w);
        xb[i] = o;
    }
}

// ---------- step 1: fused histogram (both hops) ----------
__launch_bounds__(256)
__global__ void hist_kernel(const int* __restrict__ row1, int e1, int* __restrict__ c1,
                            const int* __restrict__ row2, int e2, int* __restrict__ c2) {
    const int i = blockIdx.x * 256 + threadIdx.x;
    if (i < e1) {
        atomicAdd(&c1[row1[i]], 1);
    } else {
        const int j = i - e1;
        if (j < e2) atomicAdd(&c2[row2[j]], 1);
    }
}

// ---------- step 2: 2-pass exclusive scan, one block per hop ----------
__launch_bounds__(1024)
__global__ void exscan_kernel(int* __restrict__ a0, int* __restrict__ a1, int n) {
    int* a = (blockIdx.x == 0) ? a0 : a1;
    const int tid  = threadIdx.x;
    const int lane = tid & 63;
    const int wid  = tid >> 6;
    const int ipt  = (n + 1023) >> 10;          // items per thread
    const int begin = tid * ipt;
    const int end   = min(begin + ipt, n);

    int sum = 0;
    for (int i = begin; i < end; ++i) sum += a[i];

    // block exclusive scan of per-thread sums
    int acc = sum;
    #pragma unroll
    for (int d = 1; d < 64; d <<= 1) {
        int t = __shfl_up(acc, d);
        if (lane >= d) acc += t;
    }
    __shared__ int wsum[16];
    if (lane == 63) wsum[wid] = acc;
    __syncthreads();
    if (wid == 0) {
        int wv = (lane < 16) ? wsum[lane] : 0;
        int wacc = wv;
        #pragma unroll
        for (int d = 1; d < 16; d <<= 1) {
            int t = __shfl_up(wacc, d);
            if (lane >= d) wacc += t;
        }
        if (lane < 16) wsum[lane] = wacc - wv;  // exclusive wave offsets
    }
    __syncthreads();

    int run = acc - sum + wsum[wid];            // thread's exclusive prefix
    for (int i = begin; i < end; ++i) {
        const int v = a[i];
        a[i] = run;
        run += v;
    }
}

// ---------- step 3: fused bin (both hops); starts arrays immutable ----------
__launch_bounds__(256)
__global__ void bin_kernel(const int* __restrict__ row1, const int* __restrict__ col1,
                           const float* __restrict__ vals1, int e1,
                           const int* __restrict__ starts1, int* __restrict__ cur1,
                           int2* __restrict__ edges1,
                           const int* __restrict__ row2, const int* __restrict__ col2,
                           const float* __restrict__ vals2, int e2,
                           const int* __restrict__ starts2, int* __restrict__ cur2,
                           int2* __restrict__ edges2) {
    const int i = blockIdx.x * 256 + threadIdx.x;
    if (i < e1) {
        const int r = row1[i];
        const int p = starts1[r] + atomicAdd(&cur1[r], 1);
        edges1[p] = make_int2(col1[i], __float_as_int(vals1[i]));
    } else {
        const int j = i - e1;
        if (j < e2) {
            const int r = row2[j];
            const int p = starts2[r] + atomicAdd(&cur2[r], 1);
            edges2[p] = make_int2(col2[j], __float_as_int(vals2[j]));
        }
    }
}

// ---------- step 4: fused gather (both hops), bf16 x, one wave per row ----------
__launch_bounds__(256)
__global__ void spmm_gather_b(const int* __restrict__ starts1, const int2* __restrict__ edges1, int e1cnt,
                              const int* __restrict__ starts2, const int2* __restrict__ edges2, int e2cnt,
                              const unsigned short* __restrict__ xb,
                              float* __restrict__ out, int n_rows) {
    const int gwave = (int)((blockIdx.x * 256u + threadIdx.x) >> 6);
    const int lane  = threadIdx.x & 63;
    const bool hop2 = gwave >= n_rows;
    const int  rowi = hop2 ? gwave - n_rows : gwave;
    if (rowi >= n_rows) return;
    const int*  starts = hop2 ? starts2 : starts1;
    const int2* edges  = hop2 ? edges2  : edges1;
    const int   ecnt   = hop2 ? e2cnt   : e1cnt;

    int start = starts[rowi];
    int end   = starts[rowi + 1];
    if (start < 0) start = 0;
    if (end > ecnt) end = ecnt;

    float accx = 0.f, accy = 0.f;
    int j = start;
    for (; j + 3 < end; j += 4) {               // 4 row-loads in flight
        const int2 ea = edges[j], eb = edges[j + 1], ec = edges[j + 2], ed = edges[j + 3];
        const unsigned ua = *((const unsigned*)(xb + (size_t)ea.x * D) + lane);
        const unsigned ub = *((const unsigned*)(xb + (size_t)eb.x * D) + lane);
        const unsigned uc = *((const unsigned*)(xb + (size_t)ec.x * D) + lane);
        const unsigned ud = *((const unsigned*)(xb + (size_t)ed.x * D) + lane);
        const float va = __int_as_float(ea.y), vb = __int_as_float(eb.y);
        const float vc = __int_as_float(ec.y), vd = __int_as_float(ed.y);
        accx += va * __uint_as_float(ua << 16);
        accy += va * __uint_as_float(ua & 0xffff0000u);
        accx += vb * __uint_as_float(ub << 16);
        accy += vb * __uint_as_float(ub & 0xffff0000u);
        accx += vc * __uint_as_float(uc << 16);
        accy += vc * __uint_as_float(uc & 0xffff0000u);
        accx += vd * __uint_as_float(ud << 16);
        accy += vd * __uint_as_float(ud & 0xffff0000u);
    }
    for (; j < end; ++j) {
        const int2 e = edges[j];
        const unsigned u = *((const unsigned*)(xb + (size_t)e.x * D) + lane);
        const float v = __int_as_float(e.y);
        accx += v * __uint_as_float(u << 16);
        accy += v * __uint_as_float(u & 0xffff0000u);
    }
    ((float2*)(out + (size_t)rowi * OUT_STRIDE + (hop2 ? D : 0)))[lane] =
        make_float2(accx, accy);
}

// ---------- fp32 fallback gather (if ws can't hold xb) ----------
__launch_bounds__(256)
__global__ void spmm_gather_f(const int* __restrict__ starts1, const int2* __restrict__ edges1, int e1cnt,
                              const int* __restrict__ starts2, const int2* __restrict__ edges2, int e2cnt,
                              const float* __restrict__ x,
                              float* __restrict__ out, int n_rows) {
    const int gwave = (int)((blockIdx.x * 256u + threadIdx.x) >> 6);
    const int lane  = threadIdx.x & 63;
    const bool hop2 = gwave >= n_rows;
    const int  rowi = hop2 ? gwave - n_rows : gwave;
    if (rowi >= n_rows) return;
    const int*  starts = hop2 ? starts2 : starts1;
    const int2* edges  = hop2 ? edges2  : edges1;
    const int   ecnt   = hop2 ? e2cnt   : e1cnt;

    int start = starts[rowi];
    int end   = starts[rowi + 1];
    if (start < 0) start = 0;
    if (end > ecnt) end = ecnt;

    float2 acc = make_float2(0.f, 0.f);
    int j = start;
    for (; j + 1 < end; j += 2) {
        const int2 e0 = edges[j];
        const int2 e1 = edges[j + 1];
        const float v0 = __int_as_float(e0.y);
        const float v1 = __int_as_float(e1.y);
        const float2 a0 = ((const float2*)x)[(size_t)e0.x * (D / 2) + lane];
        const float2 a1 = ((const float2*)x)[(size_t)e1.x * (D / 2) + lane];
        acc.x += v0 * a0.x; acc.y += v0 * a0.y;
        acc.x += v1 * a1.x; acc.y += v1 * a1.y;
    }
    if (j < end) {
        const int2 e = edges[j];
        const float v = __int_as_float(e.y);
        const float2 a = ((const float2*)x)[(size_t)e.x * (D / 2) + lane];
        acc.x += v * a.x; acc.y += v * a.y;
    }
    ((float2*)(out + (size_t)rowi * OUT_STRIDE + (hop2 ? D : 0)))[lane] = acc;
}

extern "C" void kernel_launch(void* const* d_in, const int* in_sizes, int n_in,
                              void* d_out, int out_size, void* d_ws, size_t ws_size,
                              hipStream_t stream) {
    const float* x     = (const float*)d_in[0];
    const int*   row1  = (const int*)  d_in[1];
    const int*   col1  = (const int*)  d_in[2];
    const float* vals1 = (const float*)d_in[3];
    const int*   row2  = (const int*)  d_in[4];
    const int*   col2  = (const int*)  d_in[5];
    const float* vals2 = (const float*)d_in[6];
    float* out = (float*)d_out;

    const int e1 = in_sizes[1];
    const int e2 = in_sizes[4];
    const int n_rows = out_size / OUT_STRIDE;    // 50000
    const int nx = in_sizes[0];                  // 50000*128

    // workspace layout, 16B-aligned regions
    const size_t S = (((size_t)(n_rows + 1) * sizeof(int)) + 15) & ~(size_t)15;
    const size_t starts1_off = 0;
    const size_t starts2_off = S;
    const size_t cur1_off    = 2 * S;
    const size_t cur2_off    = 2 * S + (size_t)n_rows * sizeof(int);
    const size_t zero_bytes  = 2 * S + 2 * (size_t)n_rows * sizeof(int);
    const size_t edges1_off  = (zero_bytes + 15) & ~(size_t)15;
    const size_t edges2_off  = edges1_off + (size_t)e1 * sizeof(int2);
    const size_t xb_off      = edges2_off + (size_t)e2 * sizeof(int2);
    const size_t ws_with_xb  = xb_off + (size_t)nx * sizeof(unsigned short);

    int*  starts1 = (int*)((char*)d_ws + starts1_off);
    int*  starts2 = (int*)((char*)d_ws + starts2_off);
    int*  cur1    = (int*)((char*)d_ws + cur1_off);
    int*  cur2    = (int*)((char*)d_ws + cur2_off);
    int2* edges1  = (int2*)((char*)d_ws + edges1_off);
    int2* edges2  = (int2*)((char*)d_ws + edges2_off);
    unsigned short* xb = (unsigned short*)((char*)d_ws + xb_off);
    const bool use_bf16 = (ws_size >= ws_with_xb);

    // zero starts1, starts2, cur1, cur2 (contiguous prefix)
    hipMemsetAsync(d_ws, 0, zero_bytes, stream);

    if (use_bf16) {
        cvt_kernel<<<(nx / 4 + 255) / 256, 256, 0, stream>>>(
            (const float4*)x, (ushort4*)xb, nx / 4);
    }

    const int etot = e1 + e2;
    hist_kernel<<<(etot + 255) / 256, 256, 0, stream>>>(row1, e1, starts1, row2, e2, starts2);

    exscan_kernel<<<2, 1024, 0, stream>>>(starts1, starts2, n_rows + 1);

    bin_kernel<<<(etot + 255) / 256, 256, 0, stream>>>(
        row1, col1, vals1, e1, starts1, cur1, edges1,
        row2, col2, vals2, e2, starts2, cur2, edges2);

    const int gblocks = (2 * n_rows * 64 + 255) / 256;
    if (use_bf16) {
        spmm_gather_b<<<gblocks, 256, 0, stream>>>(
            starts1, edges1, e1, starts2, edges2, e2, xb, out, n_rows);
    } else {
        spmm_gather_f<<<gblocks, 256, 0, stream>>>(
            starts1, edges1, e1, starts2, edges2, e2, x, out, n_rows);
    }
}